// Round 1
// baseline (96.067 us; speedup 1.0000x reference)
//
#include <hip/hip_runtime.h>

// ConformerModel joint-network: out[b,t,u,c] = enc_proj[b,t,c] + dec_proj[b,u,c]
// B=4, T=256, U=64, D=512, C=1024.  Output 4*256*64*1024 fp32 = 256 MiB.
//
// Strategy: (1) one tiled fp32 GEMM kernel computes both projections into
// workspace (P_enc 1024x1024, P_dec 256x1024); (2) a broadcast-add kernel
// streams the 256 MiB output with coalesced nontemporal float4 stores.

#define KBLK 64
#define TILE 64
#define LDSP 68   // padded LDS row (floats): (k*68+m)%32 spreads banks

typedef float v4f __attribute__((ext_vector_type(4)));

__global__ __launch_bounds__(256) void proj_gemm(
    const float* __restrict__ Xe,   // (1024, 512) encoder rows
    const float* __restrict__ Xd,   // (256, 512)  decoder rows
    const float* __restrict__ W,    // (1024, 1024) row-major; enc uses cols [0,512), dec [512,1024)
    float* __restrict__ Pe,         // (1024, 1024)
    float* __restrict__ Pd)         // (256, 1024)
{
    const int tid = threadIdx.x;
    const int tx  = tid & 15;        // c sub-tile
    const int ty  = tid >> 4;        // m sub-tile
    const int cBase = blockIdx.x * TILE;

    const float* X;
    float*       P;
    int wofs, mBase;
    if (blockIdx.y < 16) { X = Xe; P = Pe; wofs = 0;   mBase = blockIdx.y * TILE; }
    else                 { X = Xd; P = Pd; wofs = 512; mBase = (blockIdx.y - 16) * TILE; }

    __shared__ float As[KBLK][LDSP];   // As[k][m]
    __shared__ float Bs[KBLK][LDSP];   // Bs[k][c]

    float acc[4][4] = {};

    for (int kb = 0; kb < 512; kb += KBLK) {
        // Stage 64x64 A-tile and 64x64 W-tile (transposed to [k][m]) into LDS.
        // 4096 floats each; 256 threads * 4 float4 per operand.
#pragma unroll
        for (int p = 0; p < 4; ++p) {
            int s   = tid + p * 256;     // float4 slot 0..1023
            int row = s >> 4;            // 16 float4-slots per 64-float row
            int kk  = (s & 15) << 2;
            float4 va = *(const float4*)&X[(size_t)(mBase + row) * 512 + kb + kk];
            As[kk + 0][row] = va.x; As[kk + 1][row] = va.y;
            As[kk + 2][row] = va.z; As[kk + 3][row] = va.w;
            float4 vb = *(const float4*)&W[(size_t)(cBase + row) * 1024 + wofs + kb + kk];
            Bs[kk + 0][row] = vb.x; Bs[kk + 1][row] = vb.y;
            Bs[kk + 2][row] = vb.z; Bs[kk + 3][row] = vb.w;
        }
        __syncthreads();

#pragma unroll 8
        for (int k = 0; k < KBLK; ++k) {
            float4 a = *(const float4*)&As[k][ty * 4];
            float4 b = *(const float4*)&Bs[k][tx * 4];
            float av[4] = {a.x, a.y, a.z, a.w};
            float bv[4] = {b.x, b.y, b.z, b.w};
#pragma unroll
            for (int i = 0; i < 4; ++i)
#pragma unroll
                for (int j = 0; j < 4; ++j)
                    acc[i][j] += av[i] * bv[j];
        }
        __syncthreads();
    }

#pragma unroll
    for (int i = 0; i < 4; ++i) {
        float4 r = make_float4(acc[i][0], acc[i][1], acc[i][2], acc[i][3]);
        *(float4*)&P[(size_t)(mBase + ty * 4 + i) * 1024 + cBase + tx * 4] = r;
    }
}

__global__ __launch_bounds__(256) void bcast_add(
    const float* __restrict__ Pe,   // (1024, 1024)  [b*T+t][c]
    const float* __restrict__ Pd,   // (256, 1024)   [b*U+u][c]
    float* __restrict__ out)        // (1024, 64, 1024)
{
    const int bt = blockIdx.x;        // b*256 + t
    const int b  = bt >> 8;
    const int c  = threadIdx.x << 2;  // 256 threads * 4 floats = full C row

    const float4 e = *(const float4*)&Pe[(size_t)bt * 1024 + c];
    const float* pd = &Pd[(size_t)b * 64 * 1024 + c];
    float*       po = &out[(size_t)bt * 64 * 1024 + c];

#pragma unroll 4
    for (int u = 0; u < 64; ++u) {
        float4 d = *(const float4*)&pd[(size_t)u * 1024];
        v4f r = {e.x + d.x, e.y + d.y, e.z + d.z, e.w + d.w};
        __builtin_nontemporal_store(r, (v4f*)&po[(size_t)u * 1024]);
    }
}

extern "C" void kernel_launch(void* const* d_in, const int* in_sizes, int n_in,
                              void* d_out, int out_size, void* d_ws, size_t ws_size,
                              hipStream_t stream) {
    const float* enc = (const float*)d_in[0];   // (4,256,512)
    const float* dec = (const float*)d_in[1];   // (4,64,512)
    const float* W   = (const float*)d_in[2];   // (1024,1024)
    float* out = (float*)d_out;

    float* Pe = (float*)d_ws;                       // 1024*1024 floats = 4 MiB
    float* Pd = Pe + (size_t)1024 * 1024;           // 256*1024  floats = 1 MiB

    // 16 c-tiles x (16 enc m-tiles + 4 dec m-tiles)
    proj_gemm<<<dim3(16, 20), 256, 0, stream>>>(enc, dec, W, Pe, Pd);
    // one block per (b,t); each writes a contiguous 256 KiB chunk
    bcast_add<<<dim3(1024), 256, 0, stream>>>(Pe, Pd, out);
}

// Round 2
// 84.139 us; speedup vs baseline: 1.1418x; 1.1418x over previous
//
#include <hip/hip_runtime.h>
#include <hip/hip_bf16.h>

// ConformerModel joint-network: out[b,t,u,c] = enc_proj[b,t,c] + dec_proj[b,u,c]
// B=4, T=256, U=64, D=512, C=1024.  Output 4*256*64*1024 fp32 = 256 MiB.
//
// Stage 1: bf16-MFMA projection GEMM (direct global->reg fragments, no LDS).
//          P[m][c] = sum_k X[m][k] * W[c][wofs+k], K=512, fp32 accumulate.
// Stage 2: broadcast-add streaming the 256 MiB output (write-bound, ~40us).

typedef float v4f  __attribute__((ext_vector_type(4)));
typedef float f32x4 __attribute__((ext_vector_type(4)));
typedef __attribute__((ext_vector_type(8))) short short8;   // 8 bf16 in 4 VGPRs

__device__ inline short bf16_of(float f) {
    __hip_bfloat16 h = __float2bfloat16(f);   // RNE
    return *reinterpret_cast<short*>(&h);
}

__device__ inline short8 load_cvt_bf16x8(const float* __restrict__ p) {
    float4 lo = *(const float4*)p;
    float4 hi = *(const float4*)(p + 4);
    short8 r;
    r[0] = bf16_of(lo.x); r[1] = bf16_of(lo.y); r[2] = bf16_of(lo.z); r[3] = bf16_of(lo.w);
    r[4] = bf16_of(hi.x); r[5] = bf16_of(hi.y); r[6] = bf16_of(hi.z); r[7] = bf16_of(hi.w);
    return r;
}

// Grid: (16 c-tiles, 20 m-tiles[16 enc + 4 dec]), 256 threads = 4 waves.
// Block computes 64x64 of P; wave w owns the 32x32 sub-tile (w>>1, w&1),
// as 2x2 fragments of 16x16, K-loop in steps of 32.
__global__ __launch_bounds__(256) void proj_gemm_mfma(
    const float* __restrict__ Xe,   // (1024, 512)
    const float* __restrict__ Xd,   // (256, 512)
    const float* __restrict__ W,    // (1024, 1024); enc cols [0,512), dec [512,1024)
    float* __restrict__ Pe,         // (1024, 1024)
    float* __restrict__ Pd)         // (256, 1024)
{
    const int tid  = threadIdx.x;
    const int wave = tid >> 6;
    const int lane = tid & 63;
    const int l16  = lane & 15;
    const int kq   = lane >> 4;         // 0..3

    const float* X; float* P; int wofs, mBase;
    if (blockIdx.y < 16) { X = Xe; P = Pe; wofs = 0;   mBase = blockIdx.y * 64; }
    else                 { X = Xd; P = Pd; wofs = 512; mBase = (blockIdx.y - 16) * 64; }
    const int cBase = blockIdx.x * 64;

    const int wm = (wave >> 1) * 32;
    const int wn = (wave & 1) * 32;

    // Per-lane fragment row pointers. A: rows of X; B: rows of W (k contiguous).
    const float* xr0 = X + (size_t)(mBase + wm + l16) * 512;
    const float* xr1 = xr0 + (size_t)16 * 512;
    const float* wr0 = W + (size_t)(cBase + wn + l16) * 1024 + wofs;
    const float* wr1 = wr0 + (size_t)16 * 1024;

    f32x4 acc00 = {0.f, 0.f, 0.f, 0.f};
    f32x4 acc01 = {0.f, 0.f, 0.f, 0.f};
    f32x4 acc10 = {0.f, 0.f, 0.f, 0.f};
    f32x4 acc11 = {0.f, 0.f, 0.f, 0.f};

#pragma unroll 4
    for (int kb = 0; kb < 512; kb += 32) {
        const int k = kb + kq * 8;      // lane's 8 contiguous k values
        short8 a0 = load_cvt_bf16x8(xr0 + k);
        short8 a1 = load_cvt_bf16x8(xr1 + k);
        short8 b0 = load_cvt_bf16x8(wr0 + k);
        short8 b1 = load_cvt_bf16x8(wr1 + k);
        acc00 = __builtin_amdgcn_mfma_f32_16x16x32_bf16(a0, b0, acc00, 0, 0, 0);
        acc01 = __builtin_amdgcn_mfma_f32_16x16x32_bf16(a0, b1, acc01, 0, 0, 0);
        acc10 = __builtin_amdgcn_mfma_f32_16x16x32_bf16(a1, b0, acc10, 0, 0, 0);
        acc11 = __builtin_amdgcn_mfma_f32_16x16x32_bf16(a1, b1, acc11, 0, 0, 0);
    }

    // D mapping: col = lane&15, row = 4*(lane>>4) + reg.
    float* p0 = P + (size_t)(mBase + wm) * 1024 + cBase + wn;
#pragma unroll
    for (int r = 0; r < 4; ++r) {
        const int row = kq * 4 + r;
        p0[(size_t)row * 1024        + l16     ] = acc00[r];
        p0[(size_t)row * 1024        + l16 + 16] = acc01[r];
        p0[(size_t)(row + 16) * 1024 + l16     ] = acc10[r];
        p0[(size_t)(row + 16) * 1024 + l16 + 16] = acc11[r];
    }
}

__global__ __launch_bounds__(256) void bcast_add(
    const float* __restrict__ Pe,   // (1024, 1024)  [b*T+t][c]
    const float* __restrict__ Pd,   // (256, 1024)   [b*U+u][c]
    float* __restrict__ out)        // (1024, 64, 1024)
{
    const int bt = blockIdx.x;        // b*256 + t
    const int b  = bt >> 8;
    const int c  = threadIdx.x << 2;  // 256 threads * 4 floats = full C row

    const float4 e = *(const float4*)&Pe[(size_t)bt * 1024 + c];
    const float* pd = &Pd[(size_t)b * 64 * 1024 + c];
    float*       po = &out[(size_t)bt * 64 * 1024 + c];

#pragma unroll 4
    for (int u = 0; u < 64; ++u) {
        float4 d = *(const float4*)&pd[(size_t)u * 1024];
        v4f r = {e.x + d.x, e.y + d.y, e.z + d.z, e.w + d.w};
        __builtin_nontemporal_store(r, (v4f*)&po[(size_t)u * 1024]);
    }
}

extern "C" void kernel_launch(void* const* d_in, const int* in_sizes, int n_in,
                              void* d_out, int out_size, void* d_ws, size_t ws_size,
                              hipStream_t stream) {
    const float* enc = (const float*)d_in[0];   // (4,256,512)
    const float* dec = (const float*)d_in[1];   // (4,64,512)
    const float* W   = (const float*)d_in[2];   // (1024,1024)
    float* out = (float*)d_out;

    float* Pe = (float*)d_ws;                       // 1024*1024 floats = 4 MiB
    float* Pd = Pe + (size_t)1024 * 1024;           // 256*1024  floats = 1 MiB

    proj_gemm_mfma<<<dim3(16, 20), 256, 0, stream>>>(enc, dec, W, Pe, Pd);
    bcast_add<<<dim3(1024), 256, 0, stream>>>(Pe, Pd, out);
}

// Round 3
// 77.838 us; speedup vs baseline: 1.2342x; 1.0809x over previous
//
#include <hip/hip_runtime.h>
#include <hip/hip_bf16.h>

// out[b,t,u,c] = enc[b,t,:]·W[c,:512] + dec[b,u,:]·W[c,512:]
// B=4, T=256, U=64, D=512, C=1024. Output 256 MiB fp32 (write floor ~39us).
//
// K1 cvt:  fp32 -> bf16 for enc/dec/W (once, outside the GEMM loop).
// K2 gemm: bf16-MFMA projections, direct global->reg fragments, no LDS.
// K3 add:  broadcast-add streaming the output with nontemporal float4.

typedef float v4f   __attribute__((ext_vector_type(4)));
typedef float f32x4 __attribute__((ext_vector_type(4)));
typedef __attribute__((ext_vector_type(8))) short short8;
typedef __attribute__((ext_vector_type(4))) short short4v;

__device__ inline short bf16_of(float f) {
    __hip_bfloat16 h = __float2bfloat16(f);   // RNE
    return *reinterpret_cast<short*>(&h);
}

// ---------------- K1: fp32 -> bf16 conversion --------------------------------
// Ranges in float4 units: enc 131072, dec 32768, W 262144  (total 425984).
__global__ __launch_bounds__(256) void cvt_fp32_bf16(
    const float* __restrict__ enc, const float* __restrict__ dec,
    const float* __restrict__ W,
    ushort* __restrict__ enc_bf, ushort* __restrict__ dec_bf,
    ushort* __restrict__ W_bf)
{
    const int N1 = 131072, N2 = 32768;
    int i = blockIdx.x * 256 + threadIdx.x;
    const float* src; ushort* dst; int j;
    if (i < N1)           { src = enc; dst = enc_bf; j = i; }
    else if (i < N1 + N2) { src = dec; dst = dec_bf; j = i - N1; }
    else                  { src = W;   dst = W_bf;   j = i - N1 - N2; }
    float4 v = *(const float4*)&src[(size_t)j * 4];
    short4v o;
    o[0] = bf16_of(v.x); o[1] = bf16_of(v.y);
    o[2] = bf16_of(v.z); o[3] = bf16_of(v.w);
    *(short4v*)&dst[(size_t)j * 4] = o;
}

// ---------------- K2: bf16 MFMA projection GEMM ------------------------------
// Grid (16 c-tiles, 40 m-tiles[32 enc + 8 dec]); block = 32(m) x 64(c).
// Wave w: wm=(w>>1)*16, wn=(w&1)*32 -> one A-frag, two B-frags, 2 MFMA/k-step.
__global__ __launch_bounds__(256) void proj_gemm_bf16(
    const ushort* __restrict__ Xe,  // (1024, 512) bf16
    const ushort* __restrict__ Xd,  // (256, 512)  bf16
    const ushort* __restrict__ W,   // (1024, 1024) bf16; enc cols [0,512), dec [512,1024)
    float* __restrict__ Pe,         // (1024, 1024)
    float* __restrict__ Pd)         // (256, 1024)
{
    const int tid  = threadIdx.x;
    const int wave = tid >> 6;
    const int lane = tid & 63;
    const int l16  = lane & 15;
    const int kq   = lane >> 4;

    const ushort* X; float* P; int wofs, mBase;
    if (blockIdx.y < 32) { X = Xe; P = Pe; wofs = 0;   mBase = blockIdx.y * 32; }
    else                 { X = Xd; P = Pd; wofs = 512; mBase = (blockIdx.y - 32) * 32; }
    const int cBase = blockIdx.x * 64;

    const int wm = (wave >> 1) * 16;
    const int wn = (wave & 1) * 32;

    const ushort* xr  = X + (size_t)(mBase + wm + l16) * 512;
    const ushort* wr0 = W + (size_t)(cBase + wn + l16) * 1024 + wofs;
    const ushort* wr1 = wr0 + (size_t)16 * 1024;

    f32x4 acc0 = {0.f, 0.f, 0.f, 0.f};
    f32x4 acc1 = {0.f, 0.f, 0.f, 0.f};

#pragma unroll 4
    for (int kb = 0; kb < 512; kb += 32) {
        const int k = kb + kq * 8;
        short8 a  = *(const short8*)&xr[k];
        short8 b0 = *(const short8*)&wr0[k];
        short8 b1 = *(const short8*)&wr1[k];
        acc0 = __builtin_amdgcn_mfma_f32_16x16x32_bf16(a, b0, acc0, 0, 0, 0);
        acc1 = __builtin_amdgcn_mfma_f32_16x16x32_bf16(a, b1, acc1, 0, 0, 0);
    }

    float* p0 = P + (size_t)(mBase + wm) * 1024 + cBase + wn;
#pragma unroll
    for (int r = 0; r < 4; ++r) {
        const int row = kq * 4 + r;
        p0[(size_t)row * 1024 + l16     ] = acc0[r];
        p0[(size_t)row * 1024 + l16 + 16] = acc1[r];
    }
}

// -------- fallback GEMM (inline cvt, R2-proven) if ws is too small ----------
__device__ inline short8 load_cvt_bf16x8(const float* __restrict__ p) {
    float4 lo = *(const float4*)p;
    float4 hi = *(const float4*)(p + 4);
    short8 r;
    r[0] = bf16_of(lo.x); r[1] = bf16_of(lo.y); r[2] = bf16_of(lo.z); r[3] = bf16_of(lo.w);
    r[4] = bf16_of(hi.x); r[5] = bf16_of(hi.y); r[6] = bf16_of(hi.z); r[7] = bf16_of(hi.w);
    return r;
}

__global__ __launch_bounds__(256) void proj_gemm_mfma_f32(
    const float* __restrict__ Xe, const float* __restrict__ Xd,
    const float* __restrict__ W, float* __restrict__ Pe, float* __restrict__ Pd)
{
    const int tid  = threadIdx.x;
    const int wave = tid >> 6;
    const int lane = tid & 63;
    const int l16  = lane & 15;
    const int kq   = lane >> 4;

    const float* X; float* P; int wofs, mBase;
    if (blockIdx.y < 16) { X = Xe; P = Pe; wofs = 0;   mBase = blockIdx.y * 64; }
    else                 { X = Xd; P = Pd; wofs = 512; mBase = (blockIdx.y - 16) * 64; }
    const int cBase = blockIdx.x * 64;
    const int wm = (wave >> 1) * 32;
    const int wn = (wave & 1) * 32;

    const float* xr0 = X + (size_t)(mBase + wm + l16) * 512;
    const float* xr1 = xr0 + (size_t)16 * 512;
    const float* wr0 = W + (size_t)(cBase + wn + l16) * 1024 + wofs;
    const float* wr1 = wr0 + (size_t)16 * 1024;

    f32x4 a00 = {0,0,0,0}, a01 = {0,0,0,0}, a10 = {0,0,0,0}, a11 = {0,0,0,0};
#pragma unroll 4
    for (int kb = 0; kb < 512; kb += 32) {
        const int k = kb + kq * 8;
        short8 a0 = load_cvt_bf16x8(xr0 + k);
        short8 a1 = load_cvt_bf16x8(xr1 + k);
        short8 b0 = load_cvt_bf16x8(wr0 + k);
        short8 b1 = load_cvt_bf16x8(wr1 + k);
        a00 = __builtin_amdgcn_mfma_f32_16x16x32_bf16(a0, b0, a00, 0, 0, 0);
        a01 = __builtin_amdgcn_mfma_f32_16x16x32_bf16(a0, b1, a01, 0, 0, 0);
        a10 = __builtin_amdgcn_mfma_f32_16x16x32_bf16(a1, b0, a10, 0, 0, 0);
        a11 = __builtin_amdgcn_mfma_f32_16x16x32_bf16(a1, b1, a11, 0, 0, 0);
    }
    float* p0 = P + (size_t)(mBase + wm) * 1024 + cBase + wn;
#pragma unroll
    for (int r = 0; r < 4; ++r) {
        const int row = kq * 4 + r;
        p0[(size_t)row * 1024        + l16     ] = a00[r];
        p0[(size_t)row * 1024        + l16 + 16] = a01[r];
        p0[(size_t)(row + 16) * 1024 + l16     ] = a10[r];
        p0[(size_t)(row + 16) * 1024 + l16 + 16] = a11[r];
    }
}

// ---------------- K3: broadcast-add streaming the output --------------------
__global__ __launch_bounds__(256) void bcast_add(
    const float* __restrict__ Pe,   // (1024, 1024)  [b*T+t][c]
    const float* __restrict__ Pd,   // (256, 1024)   [b*U+u][c]
    float* __restrict__ out)        // (1024, 64, 1024)
{
    const int bt    = blockIdx.x;        // b*256 + t
    const int b     = bt >> 8;
    const int uBase = blockIdx.y << 5;   // 0 or 32
    const int c     = threadIdx.x << 2;

    const float4 e = *(const float4*)&Pe[(size_t)bt * 1024 + c];
    const float* pd = &Pd[((size_t)b * 64 + uBase) * 1024 + c];
    float*       po = &out[((size_t)bt * 64 + uBase) * 1024 + c];

#pragma unroll 4
    for (int u = 0; u < 32; ++u) {
        float4 d = *(const float4*)&pd[(size_t)u * 1024];
        v4f r = {e.x + d.x, e.y + d.y, e.z + d.z, e.w + d.w};
        __builtin_nontemporal_store(r, (v4f*)&po[(size_t)u * 1024]);
    }
}

extern "C" void kernel_launch(void* const* d_in, const int* in_sizes, int n_in,
                              void* d_out, int out_size, void* d_ws, size_t ws_size,
                              hipStream_t stream) {
    const float* enc = (const float*)d_in[0];   // (4,256,512)
    const float* dec = (const float*)d_in[1];   // (4,64,512)
    const float* W   = (const float*)d_in[2];   // (1024,1024)
    float* out = (float*)d_out;

    // Workspace layout (bytes):
    //   [0,        4 MiB)  Pe
    //   [4 MiB,    5 MiB)  Pd
    //   [5 MiB,    6 MiB)  enc_bf
    //   [6 MiB, 6.25 MiB)  dec_bf
    //   [6.25 MiB, 8.25 MiB) W_bf
    char* ws = (char*)d_ws;
    float*  Pe     = (float*)(ws);
    float*  Pd     = (float*)(ws + (5u << 20) - (1u << 20));           // 4 MiB
    ushort* enc_bf = (ushort*)(ws + (5u << 20));
    ushort* dec_bf = (ushort*)(ws + (6u << 20));
    ushort* W_bf   = (ushort*)(ws + (6u << 20) + (1u << 18));

    const size_t need = (6u << 20) + (1u << 18) + (2u << 20);          // 8.25 MiB

    if (ws_size >= need) {
        cvt_fp32_bf16<<<dim3(1664), 256, 0, stream>>>(enc, dec, W, enc_bf, dec_bf, W_bf);
        proj_gemm_bf16<<<dim3(16, 40), 256, 0, stream>>>(enc_bf, dec_bf, W_bf, Pe, Pd);
    } else {
        proj_gemm_mfma_f32<<<dim3(16, 20), 256, 0, stream>>>(enc, dec, W, Pe, Pd);
    }
    bcast_add<<<dim3(1024, 2), 256, 0, stream>>>(Pe, Pd, out);
}